// Round 12
// baseline (309.427 us; speedup 1.0000x reference)
//
#include <hip/hip_runtime.h>

typedef __bf16 bf16x8 __attribute__((ext_vector_type(8)));
typedef float f32x4 __attribute__((ext_vector_type(4)));
typedef unsigned int u32x4 __attribute__((ext_vector_type(4)));
typedef unsigned int u32x2 __attribute__((ext_vector_type(2)));
typedef unsigned short u16;
typedef unsigned int u32;

#define BSZ 2
#define TSEQ 2048
#define DMODEL 1024
#define NHEAD 16
#define DHEAD 64

#define GLDS(gp, lp)                                                        \
  __builtin_amdgcn_global_load_lds(                                         \
      (const __attribute__((address_space(1))) void*)(gp),                  \
      (__attribute__((address_space(3))) void*)(lp), 16, 0, 0)

#define TRR(dst, base, OFF)                                                 \
  asm volatile("ds_read_b64_tr_b16 %0, %1 offset:" OFF                     \
               : "=v"(dst) : "v"(base) : "memory")

__device__ __forceinline__ u16 f2bf(float f) {
  return __builtin_bit_cast(u16, (__bf16)f);
}
__device__ __forceinline__ u32 pack2bf(float lo, float hi) {
  return (u32)f2bf(lo) | ((u32)f2bf(hi) << 16);
}
__device__ __forceinline__ float bf2f(u16 h) {
  return __builtin_bit_cast(float, (u32)h << 16);
}

// ---------- fused pre-pass: cvt x | transpose wqkv | transpose wout | rope table ----------
__global__ void k_prep(const float* __restrict__ x, u16* __restrict__ xb,
                       const float* __restrict__ wqkv, u16* __restrict__ wqkvT,
                       const float* __restrict__ wout, u16* __restrict__ woutT,
                       float* __restrict__ cosT, float* __restrict__ sinT) {
  __shared__ float tile[64][65];
  int blk = blockIdx.x, tid = threadIdx.x;
  if (blk < 2048) {                       // cvt x -> bf16, 8 elems/thread
    int i = blk * 256 + tid;
    const float4* f4 = (const float4*)x;
    float4 v0 = f4[i * 2], v1 = f4[i * 2 + 1];
    u32x4 o;
    o[0] = pack2bf(v0.x, v0.y); o[1] = pack2bf(v0.z, v0.w);
    o[2] = pack2bf(v1.x, v1.y); o[3] = pack2bf(v1.z, v1.w);
    ((u32x4*)xb)[i] = o;
  } else if (blk < 2816) {                // transpose wqkv [1024][3072] -> [3072][1024]
    int idx = blk - 2048;
    int n0 = (idx % 48) * 64, k0 = (idx / 48) * 64;
    int tx = tid & 63, ty = tid >> 6;
#pragma unroll
    for (int i = ty; i < 64; i += 4)
      tile[i][tx] = wqkv[(size_t)(k0 + i) * 3072 + n0 + tx];
    __syncthreads();
#pragma unroll
    for (int i = ty; i < 64; i += 4)
      wqkvT[(size_t)(n0 + i) * 1024 + k0 + tx] = f2bf(tile[tx][i]);
  } else if (blk < 3072) {                // transpose wout [1024][1024]
    int idx = blk - 2816;
    int n0 = (idx % 16) * 64, k0 = (idx / 16) * 64;
    int tx = tid & 63, ty = tid >> 6;
#pragma unroll
    for (int i = ty; i < 64; i += 4)
      tile[i][tx] = wout[(size_t)(k0 + i) * 1024 + n0 + tx];
    __syncthreads();
#pragma unroll
    for (int i = ty; i < 64; i += 4)
      woutT[(size_t)(n0 + i) * 1024 + k0 + tx] = f2bf(tile[tx][i]);
  } else {                                // rope table [2048][32]
    int idx = (blk - 3072) * 256 + tid;
    int t = idx >> 5, f = idx & 31;
    float inv_freq = powf(10000.0f, -(float)(2 * f) / 64.0f);
    float ang = (float)t * inv_freq;
    float s, c;
    sincosf(ang, &s, &c);
    cosT[idx] = c;
    sinT[idx] = s;
  }
}

// ---------------- GEMM1 fused: x @ w_qkv with RoPE+split epilogue ----------------
__global__ __launch_bounds__(256) void k_gemm_qkv(const u16* __restrict__ A,
                                                  const u16* __restrict__ Bt,
                                                  u16* __restrict__ Qh, u16* __restrict__ Kh,
                                                  u16* __restrict__ Vh,
                                                  const float* __restrict__ cosT,
                                                  const float* __restrict__ sinT) {
  const int K = DMODEL;
  __shared__ __align__(16) u16 a_lds[2][128][32];
  __shared__ __align__(16) u16 b_lds[2][128][32];
  int m0 = blockIdx.y * 128, n0 = blockIdx.x * 128;
  int tid = threadIdx.x;
  int w = tid >> 6, l = tid & 63, lr = l & 15, lg = l >> 4;
  int wr = (w >> 1) * 64, wc = (w & 1) * 64;
  int grow = l >> 2;
  int gcol = (l & 3) * 8;
  f32x4 acc[4][4] = {};

  const u16* a0 = A + (size_t)(m0 + w * 16 + grow) * K + gcol;
  const u16* a1 = A + (size_t)(m0 + (w + 4) * 16 + grow) * K + gcol;
  const u16* b0 = Bt + (size_t)(n0 + w * 16 + grow) * K + gcol;
  const u16* b1 = Bt + (size_t)(n0 + (w + 4) * 16 + grow) * K + gcol;

  int NT = K >> 5;
  GLDS(a0, &a_lds[0][w * 16][0]);
  GLDS(a1, &a_lds[0][(w + 4) * 16][0]);
  GLDS(b0, &b_lds[0][w * 16][0]);
  GLDS(b1, &b_lds[0][(w + 4) * 16][0]);

  for (int t = 0; t < NT; ++t) {
    int p = t & 1;
    if (t + 1 < NT) {
      int k0 = (t + 1) << 5;
      GLDS(a0 + k0, &a_lds[p ^ 1][w * 16][0]);
      GLDS(a1 + k0, &a_lds[p ^ 1][(w + 4) * 16][0]);
      GLDS(b0 + k0, &b_lds[p ^ 1][w * 16][0]);
      GLDS(b1 + k0, &b_lds[p ^ 1][(w + 4) * 16][0]);
      asm volatile("s_waitcnt vmcnt(4)" ::: "memory");
    } else {
      asm volatile("s_waitcnt vmcnt(0)" ::: "memory");
    }
    __builtin_amdgcn_s_barrier();
    __builtin_amdgcn_sched_barrier(0);
    bf16x8 af[4], bfv[4];
#pragma unroll
    for (int mt = 0; mt < 4; ++mt)
      af[mt] = __builtin_bit_cast(bf16x8, *(const u32x4*)&a_lds[p][wr + mt * 16 + lr][lg * 8]);
#pragma unroll
    for (int nt = 0; nt < 4; ++nt)
      bfv[nt] = __builtin_bit_cast(bf16x8, *(const u32x4*)&b_lds[p][wc + nt * 16 + lr][lg * 8]);
    __builtin_amdgcn_s_setprio(1);
#pragma unroll
    for (int mt = 0; mt < 4; ++mt)
#pragma unroll
      for (int nt = 0; nt < 4; ++nt)
        acc[mt][nt] = __builtin_amdgcn_mfma_f32_16x16x32_bf16(af[mt], bfv[nt], acc[mt][nt], 0, 0, 0);
    __builtin_amdgcn_s_setprio(0);
    __builtin_amdgcn_sched_barrier(0);
    __builtin_amdgcn_s_barrier();
  }

  // ---- fused epilogue: RoPE + head-split ----
  int sec = n0 >> 10;                         // 0=Q 1=K 2=V
  int hcol = ((n0 + wc) & 1023) >> 6;         // head index
  u16* outp = (sec == 0) ? Qh : (sec == 1) ? Kh : Vh;
  float qscale = (sec == 0) ? 0.125f : 1.0f;
#pragma unroll
  for (int mt = 0; mt < 4; ++mt)
#pragma unroll
    for (int r = 0; r < 4; ++r) {
      int row = m0 + wr + mt * 16 + lg * 4 + r;
      int b = row >> 11, tt = row & 2047;
      size_t obase = ((size_t)((b * 16 + hcol) * 2048 + tt)) * 64;
      if (sec == 2) {
#pragma unroll
        for (int nt = 0; nt < 4; ++nt)
          outp[obase + nt * 16 + lr] = f2bf(acc[mt][nt][r]);
      } else {
        float c0 = cosT[tt * 32 + lr],      s0 = sinT[tt * 32 + lr];
        float c1 = cosT[tt * 32 + 16 + lr], s1 = sinT[tt * 32 + 16 + lr];
        float v0 = acc[mt][0][r], v1 = acc[mt][1][r];
        float v2 = acc[mt][2][r], v3 = acc[mt][3][r];
        outp[obase + lr]      = f2bf((v0 * c0 - v2 * s0) * qscale);
        outp[obase + 16 + lr] = f2bf((v1 * c1 - v3 * s1) * qscale);
        outp[obase + 32 + lr] = f2bf((v2 * c0 + v0 * s0) * qscale);
        outp[obase + 48 + lr] = f2bf((v3 * c1 + v1 * s1) * qscale);
      }
    }
}

// ---------------- GEMM out: aout[4096][1024] @ woutT -> fp32, 128x64 tiles ----------------
__global__ __launch_bounds__(256) void k_gemm_out(const u16* __restrict__ A,
                                                  const u16* __restrict__ Bt,
                                                  float* __restrict__ C) {
  const int N = 1024, K = 1024;
  __shared__ __align__(16) u16 a_lds[2][128][32];
  __shared__ __align__(16) u16 b_lds[2][64][32];
  int m0 = blockIdx.y * 128, n0 = blockIdx.x * 64;
  int tid = threadIdx.x;
  int w = tid >> 6, l = tid & 63, lr = l & 15, lg = l >> 4;
  int wr = (w >> 1) * 64, wc = (w & 1) * 32;
  int grow = l >> 2;
  int gcol = (l & 3) * 8;
  f32x4 acc[4][2] = {};

  const u16* a0 = A + (size_t)(m0 + w * 16 + grow) * K + gcol;
  const u16* a1 = A + (size_t)(m0 + (w + 4) * 16 + grow) * K + gcol;
  const u16* b0 = Bt + (size_t)(n0 + w * 16 + grow) * K + gcol;

  int NT = K >> 5;
  GLDS(a0, &a_lds[0][w * 16][0]);
  GLDS(a1, &a_lds[0][(w + 4) * 16][0]);
  GLDS(b0, &b_lds[0][w * 16][0]);

  for (int t = 0; t < NT; ++t) {
    int p = t & 1;
    if (t + 1 < NT) {
      int k0 = (t + 1) << 5;
      GLDS(a0 + k0, &a_lds[p ^ 1][w * 16][0]);
      GLDS(a1 + k0, &a_lds[p ^ 1][(w + 4) * 16][0]);
      GLDS(b0 + k0, &b_lds[p ^ 1][w * 16][0]);
      asm volatile("s_waitcnt vmcnt(3)" ::: "memory");
    } else {
      asm volatile("s_waitcnt vmcnt(0)" ::: "memory");
    }
    __builtin_amdgcn_s_barrier();
    __builtin_amdgcn_sched_barrier(0);
    bf16x8 af[4], bfv[2];
#pragma unroll
    for (int mt = 0; mt < 4; ++mt)
      af[mt] = __builtin_bit_cast(bf16x8, *(const u32x4*)&a_lds[p][wr + mt * 16 + lr][lg * 8]);
#pragma unroll
    for (int nt = 0; nt < 2; ++nt)
      bfv[nt] = __builtin_bit_cast(bf16x8, *(const u32x4*)&b_lds[p][wc + nt * 16 + lr][lg * 8]);
    __builtin_amdgcn_s_setprio(1);
#pragma unroll
    for (int mt = 0; mt < 4; ++mt)
#pragma unroll
      for (int nt = 0; nt < 2; ++nt)
        acc[mt][nt] = __builtin_amdgcn_mfma_f32_16x16x32_bf16(af[mt], bfv[nt], acc[mt][nt], 0, 0, 0);
    __builtin_amdgcn_s_setprio(0);
    __builtin_amdgcn_sched_barrier(0);
    __builtin_amdgcn_s_barrier();
  }

#pragma unroll
  for (int mt = 0; mt < 4; ++mt)
#pragma unroll
    for (int nt = 0; nt < 2; ++nt)
#pragma unroll
      for (int r = 0; r < 4; ++r) {
        int row = m0 + wr + mt * 16 + lg * 4 + r;
        int col = n0 + wc + nt * 16 + lr;
        C[(size_t)row * N + col] = acc[mt][nt][r];
      }
}

// ---------------- flash attention: 8-wave teams, KVBLK=128 ----------------
// Block p: waves 0-3 -> tile qb1=31-p, waves 4-7 -> tile qb2=p. One K/V stage
// (128 rows, single-buffered) + reg-prefetch per iter serves both teams.
// Halved iteration count: one softmax reduce/defer/mrow update per 128 keys.
__global__ __launch_bounds__(512) void k_flash(const u16* __restrict__ Qg, const u16* __restrict__ Kg,
                                               const u16* __restrict__ Vg, u16* __restrict__ O) {
  __shared__ __align__(16) u16 k_lds[128][72];   // 18.4 KB
  __shared__ __align__(16) u16 vsub[2][4096];    // 16 KB: two 64-row subtiled V halves
  __shared__ __align__(16) u16 p_lds[8][16][68]; // 17.4 KB
  int pp = blockIdx.x;                  // 0..15
  int qb1 = 31 - pp, qb2 = pp;
  int bh = blockIdx.y;
  int b = bh >> 4, h = bh & 15;
  size_t hoff = (size_t)bh * TSEQ * DHEAD;
  int tid = threadIdx.x, w = tid >> 6, l = tid & 63, lr = l & 15, lg = l >> 4;
  int team = w >> 2, wt = w & 3;
  int qb_t = team ? qb2 : qb1;

  int srow = tid >> 3;        // 0..63
  int g8 = tid & 7;
  int sc8 = g8 * 8;
  u32 vtr0 = (u32)(uintptr_t)vsub + (u32)(lg * 1024 + lr * 8);

  const u16* kbase = Kg + hoff;
  const u16* vbase = Vg + hoff;

  // Q fragments for this wave's tile
  const u16* qp = Qg + hoff + (size_t)(qb_t * 64 + wt * 16 + lr) * 64 + lg * 8;
  bf16x8 qf0 = __builtin_bit_cast(bf16x8, *(const u32x4*)qp);
  bf16x8 qf1 = __builtin_bit_cast(bf16x8, *(const u32x4*)(qp + 32));

  f32x4 acc[4] = {};
  float mrow[4] = {-1e30f, -1e30f, -1e30f, -1e30f};
  float lsum[4] = {0.f, 0.f, 0.f, 0.f};   // lane-partial

  u32x4 kreg[2], vreg[2];
#pragma unroll
  for (int p = 0; p < 2; ++p) {   // prologue: tile kvt=0 (128 rows)
    int r = srow + p * 64;
    kreg[p] = *(const u32x4*)(kbase + (size_t)r * 64 + sc8);
    vreg[p] = *(const u32x4*)(vbase + (size_t)r * 64 + sc8);
  }

  int nkv = (qb1 >> 1) + 1;
  for (int kvt = 0; kvt < nkv; ++kvt) {
    __syncthreads();   // previous tile fully consumed
#pragma unroll
    for (int p = 0; p < 2; ++p) {
      int r = srow + p * 64;
      *(u32x4*)&k_lds[r][sc8] = kreg[p];
      int rr = r & 63;
      int vo = (r >> 6) * 4096 + (rr >> 2) * 256 + (g8 >> 1) * 64 + (rr & 3) * 16 + (g8 & 1) * 8;
      *(u32x4*)&vsub[0][vo] = vreg[p];
    }
    __syncthreads();   // tile ready
    if (kvt + 1 < nkv) {   // prefetch next 128 rows; hides under compute
#pragma unroll
      for (int p = 0; p < 2; ++p) {
        int r = (kvt + 1) * 128 + srow + p * 64;
        kreg[p] = *(const u32x4*)(kbase + (size_t)r * 64 + sc8);
        vreg[p] = *(const u32x4*)(vbase + (size_t)r * 64 + sc8);
      }
    }

    if (kvt * 2 > qb_t) continue;   // this team done (still stages+barriers)

    // active group count + mask start for this team's diagonal
    int ng = 8, mstart = 8;
    if (kvt == (qb_t >> 1)) {
      if (qb_t & 1) { ng = 8; mstart = 4; }
      else          { ng = 4; mstart = 0; }
    }

    // S = (Q*scale) K^T  -- 16 x (ng*16) per wave
    f32x4 s[8];
    __builtin_amdgcn_s_setprio(1);
#pragma unroll
    for (int c = 0; c < 8; ++c) {
      if (c >= ng) break;
      const u16* kp2 = &k_lds[c * 16 + lr][lg * 8];
      bf16x8 kf0 = __builtin_bit_cast(bf16x8, *(const u32x4*)kp2);
      bf16x8 kf1 = __builtin_bit_cast(bf16x8, *(const u32x4*)(kp2 + 32));
      f32x4 z = {};
      z = __builtin_amdgcn_mfma_f32_16x16x32_bf16(qf0, kf0, z, 0, 0, 0);
      s[c] = __builtin_amdgcn_mfma_f32_16x16x32_bf16(qf1, kf1, z, 0, 0, 0);
    }
    __builtin_amdgcn_s_setprio(0);
    // causal mask within diagonal tile
    int rowin = (qb_t & 1) * 64 + wt * 16 + lg * 4;
#pragma unroll
    for (int c = 0; c < 8; ++c) {
      if (c >= ng) break;
      if (c >= mstart) {
#pragma unroll
        for (int r = 0; r < 4; ++r)
          if (c * 16 + lr > rowin + r) s[c][r] = -1e30f;
      }
    }

    // online softmax over ng*16 cols; one reduce per 128 keys
    float rmax[4];
#pragma unroll
    for (int r = 0; r < 4; ++r) rmax[r] = s[0][r];
#pragma unroll
    for (int c = 1; c < 8; ++c) {
      if (c >= ng) break;
#pragma unroll
      for (int r = 0; r < 4; ++r) rmax[r] = fmaxf(rmax[r], s[c][r]);
    }
#pragma unroll
    for (int mset = 1; mset <= 8; mset <<= 1)
#pragma unroll
      for (int r = 0; r < 4; ++r)
        rmax[r] = fmaxf(rmax[r], __shfl_xor(rmax[r], mset, 64));
    bool need = (rmax[0] > mrow[0] + 8.0f) | (rmax[1] > mrow[1] + 8.0f) |
                (rmax[2] > mrow[2] + 8.0f) | (rmax[3] > mrow[3] + 8.0f);
    if (__any(need)) {
      float alpha[4];
#pragma unroll
      for (int r = 0; r < 4; ++r) {
        float mn = fmaxf(mrow[r], rmax[r]);
        alpha[r] = __expf(mrow[r] - mn);
        mrow[r] = mn;
        lsum[r] *= alpha[r];
      }
#pragma unroll
      for (int n = 0; n < 4; ++n)
#pragma unroll
        for (int r = 0; r < 4; ++r)
          acc[n][r] *= alpha[r];
    }
#pragma unroll
    for (int c = 0; c < 8; ++c) {
      if (c >= ng) break;
#pragma unroll
      for (int r = 0; r < 4; ++r) {
        float pe = __expf(s[c][r] - mrow[r]);
        s[c][r] = pe;
        lsum[r] += pe;
      }
    }

    // PV per 64-row half: P -> bf16 LDS (wave-local) -> A-frag; V via tr-reads
#pragma unroll
    for (int half = 0; half < 2; ++half) {
      if (half == 1 && ng == 4) break;
#pragma unroll
      for (int c = 0; c < 4; ++c)
#pragma unroll
        for (int r = 0; r < 4; ++r)
          p_lds[w][lg * 4 + r][c * 16 + lr] = f2bf(s[half * 4 + c][r]);
      bf16x8 pa0 = __builtin_bit_cast(bf16x8, *(const u32x4*)&p_lds[w][lr][lg * 8]);
      bf16x8 pa1 = __builtin_bit_cast(bf16x8, *(const u32x4*)&p_lds[w][lr][lg * 8 + 32]);
      u32 vtr = vtr0 + (u32)(half * 8192);
      {
        u32x2 t[8];
        TRR(t[0], vtr, "0");    TRR(t[1], vtr, "512");
        TRR(t[2], vtr, "4096"); TRR(t[3], vtr, "4608");
        TRR(t[4], vtr, "128");  TRR(t[5], vtr, "640");
        TRR(t[6], vtr, "4224"); TRR(t[7], vtr, "4736");
        asm volatile("s_waitcnt lgkmcnt(0)" ::: "memory");
        __builtin_amdgcn_sched_barrier(0);
        __builtin_amdgcn_s_setprio(1);
#pragma unroll
        for (int n2 = 0; n2 < 2; ++n2) {
          u32x4 vlo, vhi;
          vlo[0] = t[n2 * 4 + 0][0]; vlo[1] = t[n2 * 4 + 0][1];
          vlo[2] = t[n2 * 4 + 1][0]; vlo[3] = t[n2 * 4 + 1][1];
          vhi[0] = t[n2 * 4 + 2][0]; vhi[1] = t[n2 * 4 + 2][1];
          vhi[2] = t[n2 * 4 + 3][0]; vhi[3] = t[n2 * 4 + 3][1];
          acc[n2] = __builtin_amdgcn_mfma_f32_16x16x32_bf16(pa0, __builtin_bit_cast(bf16x8, vlo), acc[n2], 0, 0, 0);
          acc[n2] = __builtin_amdgcn_mfma_f32_16x16x32_bf16(pa1, __builtin_bit_cast(bf16x8, vhi), acc[n2], 0, 0, 0);
        }
        __builtin_amdgcn_s_setprio(0);
      }
      {
        u32x2 t[8];
        TRR(t[0], vtr, "256");  TRR(t[1], vtr, "768");
        TRR(t[2], vtr, "4352"); TRR(t[3], vtr, "4864");
        TRR(t[4], vtr, "384");  TRR(t[5], vtr, "896");
        TRR(t[6], vtr, "4480"); TRR(t[7], vtr, "4992");
        asm volatile("s_waitcnt lgkmcnt(0)" ::: "memory");
        __builtin_amdgcn_sched_barrier(0);
        __builtin_amdgcn_s_setprio(1);
#pragma unroll
        for (int n2 = 0; n2 < 2; ++n2) {
          int n = 2 + n2;
          u32x4 vlo, vhi;
          vlo[0] = t[n2 * 4 + 0][0]; vlo[1] = t[n2 * 4 + 0][1];
          vlo[2] = t[n2 * 4 + 1][0]; vlo[3] = t[n2 * 4 + 1][1];
          vhi[0] = t[n2 * 4 + 2][0]; vhi[1] = t[n2 * 4 + 2][1];
          vhi[2] = t[n2 * 4 + 3][0]; vhi[3] = t[n2 * 4 + 3][1];
          acc[n] = __builtin_amdgcn_mfma_f32_16x16x32_bf16(pa0, __builtin_bit_cast(bf16x8, vlo), acc[n], 0, 0, 0);
          acc[n] = __builtin_amdgcn_mfma_f32_16x16x32_bf16(pa1, __builtin_bit_cast(bf16x8, vhi), acc[n], 0, 0, 0);
        }
        __builtin_amdgcn_s_setprio(0);
      }
    }
  }

  // epilogue: reduce lane-partial sums, normalize, write this wave's tile
#pragma unroll
  for (int mset = 1; mset <= 8; mset <<= 1)
#pragma unroll
    for (int r = 0; r < 4; ++r)
      lsum[r] += __shfl_xor(lsum[r], mset, 64);
#pragma unroll
  for (int n = 0; n < 4; ++n)
#pragma unroll
    for (int r = 0; r < 4; ++r) {
      int t = qb_t * 64 + wt * 16 + lg * 4 + r;
      int dd = n * 16 + lr;
      O[(size_t)(b * TSEQ + t) * DMODEL + h * 64 + dd] = f2bf(acc[n][r] / lsum[r]);
    }
}

extern "C" void kernel_launch(void* const* d_in, const int* in_sizes, int n_in,
                              void* d_out, int out_size, void* d_ws, size_t ws_size,
                              hipStream_t stream) {
  const float* x     = (const float*)d_in[0];
  const float* w_qkv = (const float*)d_in[1];
  const float* w_out = (const float*)d_in[2];
  float* out = (float*)d_out;

  char* ws = (char*)d_ws;
  size_t off = 0;
  auto alloc = [&](size_t bytes) {
    char* p = ws + off;
    off += (bytes + 255) & ~(size_t)255;
    return p;
  };
  const size_t MT = (size_t)BSZ * TSEQ;  // 4096
  u16* xb    = (u16*)alloc(MT * DMODEL * 2);
  u16* wqkvT = (u16*)alloc((size_t)3 * DMODEL * DMODEL * 2);
  u16* woutT = (u16*)alloc((size_t)DMODEL * DMODEL * 2);
  u16* Qh    = (u16*)alloc(MT * DMODEL * 2);
  u16* Kh    = (u16*)alloc(MT * DMODEL * 2);
  u16* Vh    = (u16*)alloc(MT * DMODEL * 2);
  u16* aout  = (u16*)alloc(MT * DMODEL * 2);
  float* cosT = (float*)alloc((size_t)TSEQ * 32 * 4);
  float* sinT = (float*)alloc((size_t)TSEQ * 32 * 4);
  if (ws_size < off) return;

  k_prep<<<3328, 256, 0, stream>>>(x, xb, w_qkv, wqkvT, w_out, woutT, cosT, sinT);
  k_gemm_qkv<<<dim3(24, 32), 256, 0, stream>>>(xb, wqkvT, Qh, Kh, Vh, cosT, sinT);
  k_flash<<<dim3(16, BSZ * NHEAD), 512, 0, stream>>>(Qh, Kh, Vh, aout);
  k_gemm_out<<<dim3(16, 32), 256, 0, stream>>>(aout, woutT, out);
}